// Round 3
// baseline (212.350 us; speedup 1.0000x reference)
//
#include <hip/hip_runtime.h>
#include <hip/hip_cooperative_groups.h>

namespace cg = cooperative_groups;

// Problem constants: N1=N2=512, C=256, H=512. All fp32.
// M[i,j] = b2 + sum_h relu(hx[i,h] + hy[j,h] + b1[h]) * w2[h]
//   hx = (X @ W_sr.T) @ W1x.T, hy = (Y @ W_tg.T) @ W1y.T (+b1 folded into hy... 
//   actually b1 folded as bias on hy's columns).
//
// Single cooperative kernel, 256 blocks x 256 threads (1 block/CU), 4 phases
// separated by grid.sync(). Removes 3 kernel-launch node gaps and keeps all
// intermediates hot in cache.

#define LDS_FLOATS (2 * 64 * 68 + 64)   // phase-3 footprint (35 KB) is the max

// ---------------------------------------------------------------------------
// Proven 32x64 GEMM-NT tile (from R1/R2 gemm_nt): C[m,n] = sum_k A[m,k]*B[n,k]
// (+bias[n]).  K=256, lda=256 fixed. BK=32. 256 threads, 2x4 regs/thread.
// ---------------------------------------------------------------------------
__device__ __forceinline__ void gemm_tile_32x64(
    const float* __restrict__ A, const float* __restrict__ B,
    float* __restrict__ C, const float* __restrict__ bias,
    int m0, int n0, int N, int ldb, float* lds, int t)
{
    float* As = lds;          // 32 x 34
    float* Bs = lds + 32 * 34; // 32 x 68

    const int ti = t / 16;   // 0..15 -> rows {2ti, 2ti+1}
    const int tj = t % 16;   // 0..15 -> cols {4tj..4tj+3}

    float acc[2][4] = {};

    for (int kt = 0; kt < 256; kt += 32) {
        {
            const int m  = t / 8;
            const int k4 = (t % 8) * 4;
            float4 v = *(const float4*)&A[(m0 + m) * 256 + kt + k4];
            As[(k4 + 0) * 34 + m] = v.x;
            As[(k4 + 1) * 34 + m] = v.y;
            As[(k4 + 2) * 34 + m] = v.z;
            As[(k4 + 3) * 34 + m] = v.w;
        }
        #pragma unroll
        for (int r = 0; r < 2; r++) {
            const int id = t + r * 256;
            const int n  = id / 8;
            const int k4 = (id % 8) * 4;
            float4 v = *(const float4*)&B[(n0 + n) * ldb + kt + k4];
            Bs[(k4 + 0) * 68 + n] = v.x;
            Bs[(k4 + 1) * 68 + n] = v.y;
            Bs[(k4 + 2) * 68 + n] = v.z;
            Bs[(k4 + 3) * 68 + n] = v.w;
        }
        __syncthreads();

        #pragma unroll 8
        for (int k = 0; k < 32; k++) {
            float2 a = *(float2*)&As[k * 34 + 2 * ti];
            float4 b = *(float4*)&Bs[k * 68 + 4 * tj];
            acc[0][0] += a.x * b.x;  acc[0][1] += a.x * b.y;
            acc[0][2] += a.x * b.z;  acc[0][3] += a.x * b.w;
            acc[1][0] += a.y * b.x;  acc[1][1] += a.y * b.y;
            acc[1][2] += a.y * b.z;  acc[1][3] += a.y * b.w;
        }
        __syncthreads();
    }

    float4 bv = {0.f, 0.f, 0.f, 0.f};
    if (bias) bv = *(const float4*)&bias[n0 + 4 * tj];
    #pragma unroll
    for (int mi = 0; mi < 2; mi++) {
        const int m = m0 + 2 * ti + mi;
        float4 r;
        r.x = acc[mi][0] + bv.x;
        r.y = acc[mi][1] + bv.y;
        r.z = acc[mi][2] + bv.z;
        r.w = acc[mi][3] + bv.w;
        *(float4*)&C[m * N + n0 + 4 * tj] = r;
    }
}

// ---------------------------------------------------------------------------
// Fused kernel. grid = 256 blocks x 256 threads (1 block/CU).
// ---------------------------------------------------------------------------
__global__ __launch_bounds__(256) void fused_affinity(
    const float* __restrict__ X, const float* __restrict__ Y,
    const float* __restrict__ W_sr, const float* __restrict__ W_tg,
    const float* __restrict__ W1, const float* __restrict__ b1,
    const float* __restrict__ w2, const float* __restrict__ b2,
    float* __restrict__ ws, float* __restrict__ out)
{
    cg::grid_group grid = cg::this_grid();

    __shared__ float lds[LDS_FLOATS];

    float* Xp      = ws;             // 512*256
    float* Yp      = ws + 131072;    // 512*256
    float* hx      = ws + 262144;    // 512*512
    float* hy      = ws + 524288;    // 512*512
    float* partial = ws + 786432;    // 4 * 512*512

    const int b = blockIdx.x;
    const int t = threadIdx.x;

    // ---- Phase 1: Xp = X@W_sr.T, Yp = Y@W_tg.T (M=512,N=256,K=256) ----
    // 2 problems x (16 m-tiles x 4 n-tiles) = 128 jobs; blocks 128..255 idle.
    if (b < 128) {
        const int prob = b >> 6;
        const int tile = b & 63;
        const int m0 = (tile >> 2) * 32;
        const int n0 = (tile & 3) * 64;
        gemm_tile_32x64(prob ? Y : X, prob ? W_tg : W_sr,
                        prob ? Yp : Xp, nullptr,
                        m0, n0, 256, 256, lds, t);
    }
    grid.sync();

    // ---- Phase 2: hx = Xp@W1x.T, hy = Yp@W1y.T + b1 (M=512,N=512,K=256) ----
    // 2 problems x (16 x 8) = 256 jobs, one per block. W1 is (512 x 512);
    // W1x = W1[:, :256], W1y = W1[:, 256:] -> base offset prob*256, ldb=512.
    {
        const int prob = b >> 7;
        const int tile = b & 127;
        const int m0 = (tile >> 3) * 32;
        const int n0 = (tile & 7) * 64;
        gemm_tile_32x64(prob ? Yp : Xp, W1 + prob * 256,
                        prob ? hy : hx, prob ? b1 : nullptr,
                        m0, n0, 512, 512, lds, t);
    }
    grid.sync();

    // ---- Phase 3: partial[s][i][j] = sum_{h in 128-slab s} relu(hx+hy)*w2 ----
    // 64 tiles (64x64) x 4 slabs = 256 jobs. 4x4 regs/thread, h4 unroll 2
    // (R1 lesson: full unroll -> 256 VGPR + scratch spills).
    {
        float* xs  = lds;                 // 64 x 68
        float* ys  = lds + 64 * 68;       // 64 x 68
        float* ws2 = lds + 2 * 64 * 68;   // 64

        const int slab = b >> 6;
        const int tile = b & 63;
        const int i0 = (tile >> 3) * 64;
        const int j0 = (tile & 7) * 64;
        const int h0 = slab * 128;
        const int ti = t / 16;
        const int tj = t % 16;

        float acc[4][4] = {};

        for (int hc = 0; hc < 128; hc += 64) {
            const int hb = h0 + hc;
            #pragma unroll
            for (int s = 0; s < 4; s++) {
                const int id = t + s * 256;
                const int r  = id / 16;
                const int c4 = (id % 16) * 4;
                *(float4*)&xs[r * 68 + c4] = *(const float4*)&hx[(i0 + r) * 512 + hb + c4];
                *(float4*)&ys[r * 68 + c4] = *(const float4*)&hy[(j0 + r) * 512 + hb + c4];
            }
            if (t < 16) *(float4*)&ws2[t * 4] = *(const float4*)&w2[hb + t * 4];
            __syncthreads();

            const float* xr = xs + ti * 68;
            const float* yr = ys + tj * 68;
            #pragma unroll 2
            for (int h4 = 0; h4 < 16; h4++) {
                const int ho = h4 * 4;
                float4 w = *(const float4*)&ws2[ho];
                float4 x[4], y[4];
                #pragma unroll
                for (int m = 0; m < 4; m++) x[m] = *(const float4*)&xr[m * (16 * 68) + ho];
                #pragma unroll
                for (int n = 0; n < 4; n++) y[n] = *(const float4*)&yr[n * (16 * 68) + ho];
                #pragma unroll
                for (int m = 0; m < 4; m++) {
                    #pragma unroll
                    for (int n = 0; n < 4; n++) {
                        acc[m][n] += fmaxf(x[m].x + y[n].x, 0.f) * w.x
                                   + fmaxf(x[m].y + y[n].y, 0.f) * w.y
                                   + fmaxf(x[m].z + y[n].z, 0.f) * w.z
                                   + fmaxf(x[m].w + y[n].w, 0.f) * w.w;
                    }
                }
            }
            __syncthreads();
        }

        float* p = partial + slab * (512 * 512);
        #pragma unroll
        for (int m = 0; m < 4; m++) {
            #pragma unroll
            for (int n = 0; n < 4; n++) {
                p[(i0 + ti + 16 * m) * 512 + (j0 + tj + 16 * n)] = acc[m][n];
            }
        }
    }
    grid.sync();

    // ---- Phase 4: out = sum_s partial[s] + b2 ----
    {
        const int idx = (b * 256 + t) * 4;
        const float bb = b2[0];
        float4 r = {bb, bb, bb, bb};
        #pragma unroll
        for (int s = 0; s < 4; s++) {
            float4 p = *(const float4*)&partial[s * 262144 + idx];
            r.x += p.x; r.y += p.y; r.z += p.z; r.w += p.w;
        }
        *(float4*)&out[idx] = r;
    }
}

extern "C" void kernel_launch(void* const* d_in, const int* in_sizes, int n_in,
                              void* d_out, int out_size, void* d_ws, size_t ws_size,
                              hipStream_t stream) {
    const float* X    = (const float*)d_in[0];  // 512x256
    const float* Y    = (const float*)d_in[1];  // 512x256
    const float* W_sr = (const float*)d_in[2];  // 256x256
    const float* W_tg = (const float*)d_in[3];  // 256x256
    const float* W1   = (const float*)d_in[4];  // 512x512 (H x 2C)
    const float* b1   = (const float*)d_in[5];  // 512
    const float* w2   = (const float*)d_in[6];  // 1x512
    const float* b2   = (const float*)d_in[7];  // 1
    float* ws  = (float*)d_ws;
    float* out = (float*)d_out;

    void* args[] = {(void*)&X, (void*)&Y, (void*)&W_sr, (void*)&W_tg,
                    (void*)&W1, (void*)&b1, (void*)&w2, (void*)&b2,
                    (void*)&ws, (void*)&out};
    hipLaunchCooperativeKernel((void*)fused_affinity, dim3(256), dim3(256),
                               args, 0, stream);
}

// Round 4
// 112.148 us; speedup vs baseline: 1.8935x; 1.8935x over previous
//
#include <hip/hip_runtime.h>
#include <type_traits>

// Problem constants: N1=N2=512, C=256, H=512. Inputs/outputs fp32.
// M[i,j] = b2 + sum_h relu(hx[i,h] + hy[j,h] + b1[h]) * w2[h]
//   hx = (X @ W_sr.T) @ W1x.T, hy = (Y @ W_tg.T) @ W1y.T + b1.
//
// R3 lesson: cooperative grid.sync costs ~35us each on gfx950 (XCD L2
// flush + spin) -- 4 separate launches are much cheaper. R4: affinity core
// moved to packed-f16 (v_pk_add/max_f16 + v_dot2_f32_f16, fp32 accum):
// 1.5 VALU ops/triple instead of 3, and half the LDS bytes.

typedef _Float16 h2 __attribute__((ext_vector_type(2)));
typedef _Float16 h4 __attribute__((ext_vector_type(4)));
typedef _Float16 h8 __attribute__((ext_vector_type(8)));

// ---------------------------------------------------------------------------
// GEMM-NT: C[m,n] = sum_k A[m,k]*B[n,k] (+bias[n]).  lda=256, K=256 fixed.
// BM=32, BN=64, BK=32. 256 threads, 2x4 regs/thread. fp32 compute;
// OutT=_Float16 converts in the epilogue (bias added in fp32 first).
// blockIdx.z selects problem 0/1.
// ---------------------------------------------------------------------------
template <typename OutT>
__global__ __launch_bounds__(256) void gemm_nt(
    const float* __restrict__ A0, const float* __restrict__ A1,
    const float* __restrict__ B0, const float* __restrict__ B1,
    OutT* __restrict__ C0, OutT* __restrict__ C1,
    const float* __restrict__ bias1, int N, int ldb)
{
    const int z = blockIdx.z;
    const float* A = z ? A1 : A0;
    const float* B = z ? B1 : B0;
    OutT* Cc       = z ? C1 : C0;
    const float* bias = z ? bias1 : nullptr;

    __shared__ float As[32 * 34];
    __shared__ float Bs[32 * 68];

    const int t  = threadIdx.x;
    const int m0 = blockIdx.x * 32;
    const int n0 = blockIdx.y * 64;
    const int ti = t / 16;   // rows {2ti, 2ti+1}
    const int tj = t % 16;   // cols {4tj..4tj+3}

    float acc[2][4] = {};

    for (int kt = 0; kt < 256; kt += 32) {
        {
            const int m  = t / 8;
            const int k4 = (t % 8) * 4;
            float4 v = *(const float4*)&A[(m0 + m) * 256 + kt + k4];
            As[(k4 + 0) * 34 + m] = v.x;
            As[(k4 + 1) * 34 + m] = v.y;
            As[(k4 + 2) * 34 + m] = v.z;
            As[(k4 + 3) * 34 + m] = v.w;
        }
        #pragma unroll
        for (int r = 0; r < 2; r++) {
            const int id = t + r * 256;
            const int n  = id / 8;
            const int k4 = (id % 8) * 4;
            float4 v = *(const float4*)&B[(n0 + n) * ldb + kt + k4];
            Bs[(k4 + 0) * 68 + n] = v.x;
            Bs[(k4 + 1) * 68 + n] = v.y;
            Bs[(k4 + 2) * 68 + n] = v.z;
            Bs[(k4 + 3) * 68 + n] = v.w;
        }
        __syncthreads();

        #pragma unroll 8
        for (int k = 0; k < 32; k++) {
            float2 a = *(float2*)&As[k * 34 + 2 * ti];
            float4 b = *(float4*)&Bs[k * 68 + 4 * tj];
            acc[0][0] += a.x * b.x;  acc[0][1] += a.x * b.y;
            acc[0][2] += a.x * b.z;  acc[0][3] += a.x * b.w;
            acc[1][0] += a.y * b.x;  acc[1][1] += a.y * b.y;
            acc[1][2] += a.y * b.z;  acc[1][3] += a.y * b.w;
        }
        __syncthreads();
    }

    float4 bv = {0.f, 0.f, 0.f, 0.f};
    if (bias) bv = *(const float4*)&bias[n0 + 4 * tj];
    #pragma unroll
    for (int mi = 0; mi < 2; mi++) {
        const int m = m0 + 2 * ti + mi;
        float rx = acc[mi][0] + bv.x;
        float ry = acc[mi][1] + bv.y;
        float rz = acc[mi][2] + bv.z;
        float rw = acc[mi][3] + bv.w;
        if constexpr (std::is_same_v<OutT, float>) {
            float4 r = {rx, ry, rz, rw};
            *(float4*)&Cc[m * N + n0 + 4 * tj] = r;
        } else {
            h4 r = {(_Float16)rx, (_Float16)ry, (_Float16)rz, (_Float16)rw};
            *(h4*)&Cc[m * N + n0 + 4 * tj] = r;
        }
    }
}

// ---------------------------------------------------------------------------
// Core: partial[s][i][j] = sum_{h in 64-slab s} relu(hx[i,h]+hy[j,h])*w2[h]
// grid (8,8,8) = 512 blocks (2/CU), 256 threads, 4x4 register tile.
// f16 operands, v_dot2_f32_f16 accumulate (fp32). LDS row stride 72 halfs
// (144 B = 4 banks offset/row): x-reads broadcast, y-reads <=2-way = free.
// h-loop unroll 2 (R1 lesson: full unroll -> 256 VGPR + spills).
// ---------------------------------------------------------------------------
__global__ __launch_bounds__(256) void affinity_core(
    const _Float16* __restrict__ hx, const _Float16* __restrict__ hy,
    const float* __restrict__ w2, float* __restrict__ partial)
{
    __shared__ __align__(16) _Float16 xs[64 * 72];
    __shared__ __align__(16) _Float16 ys[64 * 72];
    __shared__ __align__(16) _Float16 ws2[64];

    const int t  = threadIdx.x;
    const int i0 = blockIdx.x * 64;
    const int j0 = blockIdx.y * 64;
    const int h0 = blockIdx.z * 64;
    const int ti = t / 16;
    const int tj = t % 16;

    // Stage 64 rows x 64 halfs for both operands (each thread: 2 float4 each)
    #pragma unroll
    for (int s = 0; s < 2; s++) {
        const int id = t + s * 256;
        const int r  = id >> 3;
        const int c8 = (id & 7) * 8;
        *(float4*)&xs[r * 72 + c8] = *(const float4*)&hx[(i0 + r) * 512 + h0 + c8];
        *(float4*)&ys[r * 72 + c8] = *(const float4*)&hy[(j0 + r) * 512 + h0 + c8];
    }
    if (t < 64) ws2[t] = (_Float16)w2[h0 + t];
    __syncthreads();

    float acc[4][4] = {};
    const _Float16* xr = xs + ti * 72;
    const _Float16* yr = ys + tj * 72;
    const h2 hz = {(_Float16)0.f, (_Float16)0.f};

    #pragma unroll 2
    for (int g = 0; g < 8; g++) {
        const int ho = g * 8;
        h8 w = *(const h8*)&ws2[ho];
        h8 x[4], y[4];
        #pragma unroll
        for (int m = 0; m < 4; m++) x[m] = *(const h8*)&xr[m * (16 * 72) + ho];
        #pragma unroll
        for (int n = 0; n < 4; n++) y[n] = *(const h8*)&yr[n * (16 * 72) + ho];
        const h2* wp = (const h2*)&w;
        #pragma unroll
        for (int m = 0; m < 4; m++) {
            const h2* xp = (const h2*)&x[m];
            #pragma unroll
            for (int n = 0; n < 4; n++) {
                const h2* yp = (const h2*)&y[n];
                float a = acc[m][n];
                #pragma unroll
                for (int p = 0; p < 4; p++) {
                    h2 s = xp[p] + yp[p];                       // v_pk_add_f16
                    s = __builtin_elementwise_max(s, hz);       // v_pk_max_f16
                    a = __builtin_amdgcn_fdot2(s, wp[p], a, false); // v_dot2_f32_f16
                }
                acc[m][n] = a;
            }
        }
    }

    float* p = partial + blockIdx.z * (512 * 512);
    #pragma unroll
    for (int m = 0; m < 4; m++) {
        #pragma unroll
        for (int n = 0; n < 4; n++) {
            p[(i0 + ti + 16 * m) * 512 + (j0 + tj + 16 * n)] = acc[m][n];
        }
    }
}

// ---------------------------------------------------------------------------
// Final reduce: out = sum_{s<8} partial[s] + b2
// ---------------------------------------------------------------------------
__global__ __launch_bounds__(256) void reduce8(
    const float* __restrict__ partial, const float* __restrict__ b2,
    float* __restrict__ out)
{
    const int idx = (blockIdx.x * 256 + threadIdx.x) * 4;
    const float bb = b2[0];
    float4 r = {bb, bb, bb, bb};
    #pragma unroll
    for (int s = 0; s < 8; s++) {
        float4 p = *(const float4*)&partial[s * 262144 + idx];
        r.x += p.x; r.y += p.y; r.z += p.z; r.w += p.w;
    }
    *(float4*)&out[idx] = r;
}

extern "C" void kernel_launch(void* const* d_in, const int* in_sizes, int n_in,
                              void* d_out, int out_size, void* d_ws, size_t ws_size,
                              hipStream_t stream) {
    const float* X    = (const float*)d_in[0];  // 512x256
    const float* Y    = (const float*)d_in[1];  // 512x256
    const float* W_sr = (const float*)d_in[2];  // 256x256
    const float* W_tg = (const float*)d_in[3];  // 256x256
    const float* W1   = (const float*)d_in[4];  // 512x512 (H x 2C)
    const float* b1   = (const float*)d_in[5];  // 512
    const float* w2   = (const float*)d_in[6];  // 1x512
    const float* b2   = (const float*)d_in[7];  // 1

    float* ws        = (float*)d_ws;
    float* Xp        = ws;                          // 512*256 f32
    float* Yp        = ws + 131072;                 // 512*256 f32
    _Float16* hx     = (_Float16*)(ws + 262144);    // 512*512 f16
    _Float16* hy     = (_Float16*)(ws + 393216);    // 512*512 f16
    float* partial   = ws + 524288;                 // 8 * 512*512 f32
    float* out       = (float*)d_out;

    // Stage 1: Xp = X @ W_sr.T ; Yp = Y @ W_tg.T   (M=512,N=256,K=256)
    gemm_nt<float><<<dim3(16, 4, 2), 256, 0, stream>>>(
        X, Y, W_sr, W_tg, Xp, Yp, nullptr, 256, 256);
    // Stage 2: hx = Xp @ W1x.T ; hy = Yp @ W1y.T + b1 -> f16 (M=512,N=512,K=256)
    gemm_nt<_Float16><<<dim3(16, 8, 2), 256, 0, stream>>>(
        Xp, Yp, W1, W1 + 256, hx, hy, b1, 512, 512);
    // Stage 3: h-split relu reduction into 8 partials (512 blocks = 2/CU)
    affinity_core<<<dim3(8, 8, 8), 256, 0, stream>>>(hx, hy, w2, partial);
    // Stage 4: sum partials + b2
    reduce8<<<256, 256, 0, stream>>>(partial, b2, out);
}

// Round 5
// 108.564 us; speedup vs baseline: 1.9560x; 1.0330x over previous
//
#include <hip/hip_runtime.h>
#include <type_traits>

// Problem constants: N1=N2=512, C=256, H=512. Inputs/outputs fp32.
// M[i,j] = b2 + sum_h relu(hx[i,h] + hy[j,h] + b1[h]) * w2[h]
//   hx = (X @ W_sr.T) @ W1x.T, hy = (Y @ W_tg.T) @ W1y.T + b1.
//
// Pipeline (all f16 data movement, fp32 accumulation via v_dot2_f32_f16):
//   gemm1 (f32 compute, f16 out) -> gemm2_f16 (dot2) -> affinity (dot2,
//   f16 partials) -> reduce8 (f32 out).
// R3 lesson: grid.sync ~35us on gfx950 -- separate launches are cheaper.
// R1 lesson: cap unrolls; full unroll -> 256 VGPR + scratch spills.

typedef _Float16 h2 __attribute__((ext_vector_type(2)));
typedef _Float16 h4 __attribute__((ext_vector_type(4)));
typedef _Float16 h8 __attribute__((ext_vector_type(8)));

// ---------------------------------------------------------------------------
// GEMM-NT stage 1: fp32 compute, f16 output. C[m,n] = sum_k A[m,k]*B[n,k].
// lda=256, K=256. BM=32, BN=64, BK=32. 256 threads, 2x4 regs/thread.
// ---------------------------------------------------------------------------
__global__ __launch_bounds__(256) void gemm_nt_f32(
    const float* __restrict__ A0, const float* __restrict__ A1,
    const float* __restrict__ B0, const float* __restrict__ B1,
    _Float16* __restrict__ C0, _Float16* __restrict__ C1,
    int N, int ldb)
{
    const int z = blockIdx.z;
    const float* A = z ? A1 : A0;
    const float* B = z ? B1 : B0;
    _Float16* Cc   = z ? C1 : C0;

    __shared__ float As[32 * 34];
    __shared__ float Bs[32 * 68];

    const int t  = threadIdx.x;
    const int m0 = blockIdx.x * 32;
    const int n0 = blockIdx.y * 64;
    const int ti = t / 16;   // rows {2ti, 2ti+1}
    const int tj = t % 16;   // cols {4tj..4tj+3}

    float acc[2][4] = {};

    for (int kt = 0; kt < 256; kt += 32) {
        {
            const int m  = t / 8;
            const int k4 = (t % 8) * 4;
            float4 v = *(const float4*)&A[(m0 + m) * 256 + kt + k4];
            As[(k4 + 0) * 34 + m] = v.x;
            As[(k4 + 1) * 34 + m] = v.y;
            As[(k4 + 2) * 34 + m] = v.z;
            As[(k4 + 3) * 34 + m] = v.w;
        }
        #pragma unroll
        for (int r = 0; r < 2; r++) {
            const int id = t + r * 256;
            const int n  = id / 8;
            const int k4 = (id % 8) * 4;
            float4 v = *(const float4*)&B[(n0 + n) * ldb + kt + k4];
            Bs[(k4 + 0) * 68 + n] = v.x;
            Bs[(k4 + 1) * 68 + n] = v.y;
            Bs[(k4 + 2) * 68 + n] = v.z;
            Bs[(k4 + 3) * 68 + n] = v.w;
        }
        __syncthreads();

        #pragma unroll 8
        for (int k = 0; k < 32; k++) {
            float2 a = *(float2*)&As[k * 34 + 2 * ti];
            float4 b = *(float4*)&Bs[k * 68 + 4 * tj];
            acc[0][0] += a.x * b.x;  acc[0][1] += a.x * b.y;
            acc[0][2] += a.x * b.z;  acc[0][3] += a.x * b.w;
            acc[1][0] += a.y * b.x;  acc[1][1] += a.y * b.y;
            acc[1][2] += a.y * b.z;  acc[1][3] += a.y * b.w;
        }
        __syncthreads();
    }

    #pragma unroll
    for (int mi = 0; mi < 2; mi++) {
        const int m = m0 + 2 * ti + mi;
        h4 r = {(_Float16)acc[mi][0], (_Float16)acc[mi][1],
                (_Float16)acc[mi][2], (_Float16)acc[mi][3]};
        *(h4*)&Cc[m * N + n0 + 4 * tj] = r;
    }
}

// ---------------------------------------------------------------------------
// GEMM-NT stage 2: f16 A (lda=256), f32 B converted to f16 in staging,
// v_dot2_f32_f16 compute (fp32 accum), fp32 bias, f16 output.
// Pair-major LDS: As2[kp][2m] stride 68 halfs, Bs2[kp][2n] stride 136 halfs
// (compute reads: A b64 broadcast-free, B b128 2-way = free).
// ---------------------------------------------------------------------------
__global__ __launch_bounds__(256) void gemm_nt_f16(
    const _Float16* __restrict__ A0, const _Float16* __restrict__ A1,
    const float* __restrict__ B0, const float* __restrict__ B1,
    _Float16* __restrict__ C0, _Float16* __restrict__ C1,
    const float* __restrict__ bias1, int N, int ldb)
{
    const int z = blockIdx.z;
    const _Float16* A = z ? A1 : A0;
    const float* B    = z ? B1 : B0;
    _Float16* Cc      = z ? C1 : C0;
    const float* bias = z ? bias1 : nullptr;

    __shared__ _Float16 As2[16 * 68];    // [kp][2m]
    __shared__ _Float16 Bs2[16 * 136];   // [kp][2n]

    const int t  = threadIdx.x;
    const int m0 = blockIdx.x * 32;
    const int n0 = blockIdx.y * 64;
    const int ti = t / 16;   // rows {2ti, 2ti+1}
    const int tj = t % 16;   // cols {4tj..4tj+3}

    float acc[2][4] = {};

    for (int kt = 0; kt < 256; kt += 32) {
        // Stage A: 32 m x 32 k f16 -> pair-major
        {
            const int m   = t >> 3;
            const int k4  = (t & 7) * 4;
            const int kp0 = k4 >> 1;
            h4 v = *(const h4*)&A[(m0 + m) * 256 + kt + k4];
            h2 lo = {v[0], v[1]}, hi = {v[2], v[3]};
            *(h2*)&As2[kp0 * 68 + 2 * m]       = lo;
            *(h2*)&As2[(kp0 + 1) * 68 + 2 * m] = hi;
        }
        // Stage B: 64 n x 32 k f32 -> f16 pair-major
        #pragma unroll
        for (int r = 0; r < 2; r++) {
            const int id  = t + r * 256;
            const int n   = id >> 3;
            const int k4  = (id & 7) * 4;
            const int kp0 = k4 >> 1;
            float4 v = *(const float4*)&B[(n0 + n) * ldb + kt + k4];
            h2 lo = {(_Float16)v.x, (_Float16)v.y};
            h2 hi = {(_Float16)v.z, (_Float16)v.w};
            *(h2*)&Bs2[kp0 * 136 + 2 * n]       = lo;
            *(h2*)&Bs2[(kp0 + 1) * 136 + 2 * n] = hi;
        }
        __syncthreads();

        #pragma unroll 8
        for (int kp = 0; kp < 16; kp++) {
            h4 a = *(const h4*)&As2[kp * 68 + 4 * ti];
            h8 b = *(const h8*)&Bs2[kp * 136 + 8 * tj];
            const h2* ap = (const h2*)&a;
            const h2* bp = (const h2*)&b;
            #pragma unroll
            for (int nj = 0; nj < 4; nj++) {
                acc[0][nj] = __builtin_amdgcn_fdot2(ap[0], bp[nj], acc[0][nj], false);
                acc[1][nj] = __builtin_amdgcn_fdot2(ap[1], bp[nj], acc[1][nj], false);
            }
        }
        __syncthreads();
    }

    float4 bv = {0.f, 0.f, 0.f, 0.f};
    if (bias) bv = *(const float4*)&bias[n0 + 4 * tj];
    #pragma unroll
    for (int mi = 0; mi < 2; mi++) {
        const int m = m0 + 2 * ti + mi;
        h4 r = {(_Float16)(acc[mi][0] + bv.x), (_Float16)(acc[mi][1] + bv.y),
                (_Float16)(acc[mi][2] + bv.z), (_Float16)(acc[mi][3] + bv.w)};
        *(h4*)&Cc[m * N + n0 + 4 * tj] = r;
    }
}

// ---------------------------------------------------------------------------
// Core: partial[s][i][j] = sum_{h in 64-slab s} relu(hx[i,h]+hy[j,h])*w2[h]
// grid (8,8,8) = 512 blocks (2/CU), 256 threads, 4x4 register tile.
// f16 operands, v_dot2_f32_f16 accumulate. f16 partial output.
// ---------------------------------------------------------------------------
__global__ __launch_bounds__(256) void affinity_core(
    const _Float16* __restrict__ hx, const _Float16* __restrict__ hy,
    const float* __restrict__ w2, _Float16* __restrict__ partial)
{
    __shared__ __align__(16) _Float16 xs[64 * 72];
    __shared__ __align__(16) _Float16 ys[64 * 72];
    __shared__ __align__(16) _Float16 ws2[64];

    const int t  = threadIdx.x;
    const int i0 = blockIdx.x * 64;
    const int j0 = blockIdx.y * 64;
    const int h0 = blockIdx.z * 64;
    const int ti = t / 16;
    const int tj = t % 16;

    #pragma unroll
    for (int s = 0; s < 2; s++) {
        const int id = t + s * 256;
        const int r  = id >> 3;
        const int c8 = (id & 7) * 8;
        *(float4*)&xs[r * 72 + c8] = *(const float4*)&hx[(i0 + r) * 512 + h0 + c8];
        *(float4*)&ys[r * 72 + c8] = *(const float4*)&hy[(j0 + r) * 512 + h0 + c8];
    }
    if (t < 64) ws2[t] = (_Float16)w2[h0 + t];
    __syncthreads();

    float acc[4][4] = {};
    const _Float16* xr = xs + ti * 72;
    const _Float16* yr = ys + tj * 72;
    const h2 hz = {(_Float16)0.f, (_Float16)0.f};

    #pragma unroll 2
    for (int g = 0; g < 8; g++) {
        const int ho = g * 8;
        h8 w = *(const h8*)&ws2[ho];
        h8 x[4], y[4];
        #pragma unroll
        for (int m = 0; m < 4; m++) x[m] = *(const h8*)&xr[m * (16 * 72) + ho];
        #pragma unroll
        for (int n = 0; n < 4; n++) y[n] = *(const h8*)&yr[n * (16 * 72) + ho];
        const h2* wp = (const h2*)&w;
        #pragma unroll
        for (int m = 0; m < 4; m++) {
            const h2* xp = (const h2*)&x[m];
            #pragma unroll
            for (int n = 0; n < 4; n++) {
                const h2* yp = (const h2*)&y[n];
                float a = acc[m][n];
                #pragma unroll
                for (int p = 0; p < 4; p++) {
                    h2 s = xp[p] + yp[p];                          // v_pk_add_f16
                    s = __builtin_elementwise_max(s, hz);          // v_pk_max_f16
                    a = __builtin_amdgcn_fdot2(s, wp[p], a, false); // v_dot2_f32_f16
                }
                acc[m][n] = a;
            }
        }
    }

    _Float16* p = partial + blockIdx.z * (512 * 512);
    #pragma unroll
    for (int m = 0; m < 4; m++) {
        #pragma unroll
        for (int n = 0; n < 4; n++) {
            p[(i0 + ti + 16 * m) * 512 + (j0 + tj + 16 * n)] = (_Float16)acc[m][n];
        }
    }
}

// ---------------------------------------------------------------------------
// Final reduce: out = sum_{s<8} partial[s] + b2  (f16 partials, f32 out)
// ---------------------------------------------------------------------------
__global__ __launch_bounds__(256) void reduce8(
    const _Float16* __restrict__ partial, const float* __restrict__ b2,
    float* __restrict__ out)
{
    const int idx = (blockIdx.x * 256 + threadIdx.x) * 4;
    const float bb = b2[0];
    float4 r = {bb, bb, bb, bb};
    #pragma unroll
    for (int s = 0; s < 8; s++) {
        h4 p = *(const h4*)&partial[s * 262144 + idx];
        r.x += (float)p[0]; r.y += (float)p[1];
        r.z += (float)p[2]; r.w += (float)p[3];
    }
    *(float4*)&out[idx] = r;
}

extern "C" void kernel_launch(void* const* d_in, const int* in_sizes, int n_in,
                              void* d_out, int out_size, void* d_ws, size_t ws_size,
                              hipStream_t stream) {
    const float* X    = (const float*)d_in[0];  // 512x256
    const float* Y    = (const float*)d_in[1];  // 512x256
    const float* W_sr = (const float*)d_in[2];  // 256x256
    const float* W_tg = (const float*)d_in[3];  // 256x256
    const float* W1   = (const float*)d_in[4];  // 512x512 (H x 2C)
    const float* b1   = (const float*)d_in[5];  // 512
    const float* w2   = (const float*)d_in[6];  // 1x512
    const float* b2   = (const float*)d_in[7];  // 1

    float* ws = (float*)d_ws;
    _Float16* Xp      = (_Float16*)ws;               // 512x256 f16 (65536 f32-eq)
    _Float16* Yp      = (_Float16*)(ws + 65536);     // 512x256 f16
    _Float16* hx      = (_Float16*)(ws + 131072);    // 512x512 f16 (131072 f32-eq)
    _Float16* hy      = (_Float16*)(ws + 262144);    // 512x512 f16
    _Float16* partial = (_Float16*)(ws + 393216);    // 8 x 512x512 f16
    float* out = (float*)d_out;

    // Stage 1: Xp = X @ W_sr.T ; Yp = Y @ W_tg.T (f32 compute, f16 out)
    gemm_nt_f32<<<dim3(16, 4, 2), 256, 0, stream>>>(
        X, Y, W_sr, W_tg, Xp, Yp, 256, 256);
    // Stage 2: hx = Xp @ W1x.T ; hy = Yp @ W1y.T + b1 (dot2-f16, f16 out)
    gemm_nt_f16<<<dim3(16, 8, 2), 256, 0, stream>>>(
        Xp, Yp, W1, W1 + 256, hx, hy, b1, 512, 512);
    // Stage 3: h-split relu reduction into 8 f16 partials (512 blocks = 2/CU)
    affinity_core<<<dim3(8, 8, 8), 256, 0, stream>>>(hx, hy, w2, partial);
    // Stage 4: sum partials + b2
    reduce8<<<256, 256, 0, stream>>>(partial, b2, out);
}

// Round 6
// 106.198 us; speedup vs baseline: 1.9996x; 1.0223x over previous
//
#include <hip/hip_runtime.h>

// Problem constants: N1=N2=512, C=256, H=512. Inputs/outputs fp32.
// M[i,j] = b2 + sum_h relu(hx[i,h] + hy[j,h] + b1[h]) * w2[h]
//   hx = (X @ W_sr.T) @ W1x.T, hy = (Y @ W_tg.T) @ W1y.T + b1.
//
// All stages move f16 data and accumulate fp32 via v_dot2_f32_f16.
// R3 lesson: grid.sync ~35us on gfx950 -- separate launches are cheaper.
// R1 lesson: cap unrolls (full unroll -> 256 VGPR + scratch spills).
// R5 lesson (cycle accounting): both GEMMs were LDS-pipe-bound; balance
// reads vs dot2 with bigger per-thread tiles + 1 block/CU grids.

typedef _Float16 h2 __attribute__((ext_vector_type(2)));
typedef _Float16 h4 __attribute__((ext_vector_type(4)));
typedef _Float16 h8 __attribute__((ext_vector_type(8)));

// ---------------------------------------------------------------------------
// GEMM-NT stage 1: Xp = X @ W_sr.T (and Y-path), f32 inputs converted to f16
// at staging, dot2 compute, f16 out. M=512, N=256, K=256, lda=ldb=256.
// BM=32, BN=32, BK=32. 128 threads, per-thread 4 rows x 2 cols.
// LDS pair-major [kp][2m], stride 72 halfs (144 B, 16B-aligned rows).
// Per kp per wave: A b128 + B b64 = ~18 cy LDS vs 16 cy VALU -> balanced.
// ---------------------------------------------------------------------------
__global__ __launch_bounds__(128) void gemm1_f16(
    const float* __restrict__ A0, const float* __restrict__ A1,
    const float* __restrict__ B0, const float* __restrict__ B1,
    _Float16* __restrict__ C0, _Float16* __restrict__ C1)
{
    const int z = blockIdx.z;
    const float* A = z ? A1 : A0;
    const float* B = z ? B1 : B0;
    _Float16* Cc   = z ? C1 : C0;

    __shared__ _Float16 As2[16 * 72];   // [kp][2m], 64 halfs used/row
    __shared__ _Float16 Bs2[16 * 72];   // [kp][2n]

    const int t  = threadIdx.x;
    const int m0 = blockIdx.x * 32;
    const int n0 = blockIdx.y * 32;
    const int ti = t >> 4;   // 0..7  -> rows 4ti..4ti+3
    const int tj = t & 15;   // 0..15 -> cols 2tj..2tj+1

    float acc[4][2] = {};

    for (int kt = 0; kt < 256; kt += 32) {
        // Stage A: 32m x 32k f32 -> f16 pair-major (2 float4 per thread)
        #pragma unroll
        for (int r = 0; r < 2; r++) {
            const int id  = t + r * 128;
            const int m   = id >> 3;
            const int k4  = (id & 7) * 4;
            const int kp0 = k4 >> 1;
            float4 v = *(const float4*)&A[(m0 + m) * 256 + kt + k4];
            h2 lo = {(_Float16)v.x, (_Float16)v.y};
            h2 hi = {(_Float16)v.z, (_Float16)v.w};
            *(h2*)&As2[kp0 * 72 + 2 * m]       = lo;
            *(h2*)&As2[(kp0 + 1) * 72 + 2 * m] = hi;
        }
        // Stage B: 32n x 32k f32 -> f16 pair-major
        #pragma unroll
        for (int r = 0; r < 2; r++) {
            const int id  = t + r * 128;
            const int n   = id >> 3;
            const int k4  = (id & 7) * 4;
            const int kp0 = k4 >> 1;
            float4 v = *(const float4*)&B[(n0 + n) * 256 + kt + k4];
            h2 lo = {(_Float16)v.x, (_Float16)v.y};
            h2 hi = {(_Float16)v.z, (_Float16)v.w};
            *(h2*)&Bs2[kp0 * 72 + 2 * n]       = lo;
            *(h2*)&Bs2[(kp0 + 1) * 72 + 2 * n] = hi;
        }
        __syncthreads();

        #pragma unroll 8
        for (int kp = 0; kp < 16; kp++) {
            h8 a = *(const h8*)&As2[kp * 72 + 8 * ti];   // rows 4ti..4ti+3
            h4 b = *(const h4*)&Bs2[kp * 72 + 4 * tj];   // cols 2tj..2tj+1
            const h2* ap = (const h2*)&a;
            const h2* bp = (const h2*)&b;
            #pragma unroll
            for (int mi = 0; mi < 4; mi++)
                #pragma unroll
                for (int nj = 0; nj < 2; nj++)
                    acc[mi][nj] = __builtin_amdgcn_fdot2(ap[mi], bp[nj],
                                                         acc[mi][nj], false);
        }
        __syncthreads();
    }

    #pragma unroll
    for (int mi = 0; mi < 4; mi++) {
        const int m = m0 + 4 * ti + mi;
        h2 r = {(_Float16)acc[mi][0], (_Float16)acc[mi][1]};
        *(h2*)&Cc[m * 256 + n0 + 2 * tj] = r;
    }
}

// ---------------------------------------------------------------------------
// GEMM-NT stage 2: hx = Xp @ W1x.T (+bias on y-path). A f16 (lda=256),
// B f32 (ldb=512, col offset prob*256) converted at staging. M=512, N=512.
// BM=32, BN=64, BK=32. 128 threads, per-thread 4x4.
// As2 stride 72 halfs, Bs2 stride 136 halfs (272 B, 16B-aligned rows).
// Per kp per wave: 2 b128 = 24 cy LDS vs 32 cy VALU -> VALU-bound.
// ---------------------------------------------------------------------------
__global__ __launch_bounds__(128) void gemm2_f16(
    const _Float16* __restrict__ A0, const _Float16* __restrict__ A1,
    const float* __restrict__ B0, const float* __restrict__ B1,
    _Float16* __restrict__ C0, _Float16* __restrict__ C1,
    const float* __restrict__ bias1)
{
    const int z = blockIdx.z;
    const _Float16* A = z ? A1 : A0;
    const float* B    = z ? B1 : B0;
    _Float16* Cc      = z ? C1 : C0;
    const float* bias = z ? bias1 : nullptr;

    __shared__ _Float16 As2[16 * 72];    // [kp][2m], 64 halfs used
    __shared__ _Float16 Bs2[16 * 136];   // [kp][2n], 128 halfs used

    const int t  = threadIdx.x;
    const int m0 = blockIdx.x * 32;
    const int n0 = blockIdx.y * 64;
    const int ti = t >> 4;   // 0..7  -> rows 4ti..4ti+3
    const int tj = t & 15;   // 0..15 -> cols 4tj..4tj+3

    float acc[4][4] = {};

    for (int kt = 0; kt < 256; kt += 32) {
        // Stage A: 32m x 32k f16 -> pair-major (1 h8 per thread)
        {
            const int m   = t >> 2;
            const int k8  = (t & 3) * 8;
            const int kp0 = k8 >> 1;
            h8 v = *(const h8*)&A[(m0 + m) * 256 + kt + k8];
            #pragma unroll
            for (int i = 0; i < 4; i++) {
                h2 p = {v[2 * i], v[2 * i + 1]};
                *(h2*)&As2[(kp0 + i) * 72 + 2 * m] = p;
            }
        }
        // Stage B: 64n x 32k f32 -> f16 pair-major (4 float4 per thread)
        #pragma unroll
        for (int r = 0; r < 4; r++) {
            const int id  = t + r * 128;
            const int n   = id >> 3;
            const int k4  = (id & 7) * 4;
            const int kp0 = k4 >> 1;
            float4 v = *(const float4*)&B[(n0 + n) * 512 + kt + k4];
            h2 lo = {(_Float16)v.x, (_Float16)v.y};
            h2 hi = {(_Float16)v.z, (_Float16)v.w};
            *(h2*)&Bs2[kp0 * 136 + 2 * n]       = lo;
            *(h2*)&Bs2[(kp0 + 1) * 136 + 2 * n] = hi;
        }
        __syncthreads();

        #pragma unroll 8
        for (int kp = 0; kp < 16; kp++) {
            h8 a = *(const h8*)&As2[kp * 72 + 8 * ti];
            h8 b = *(const h8*)&Bs2[kp * 136 + 8 * tj];
            const h2* ap = (const h2*)&a;
            const h2* bp = (const h2*)&b;
            #pragma unroll
            for (int mi = 0; mi < 4; mi++)
                #pragma unroll
                for (int nj = 0; nj < 4; nj++)
                    acc[mi][nj] = __builtin_amdgcn_fdot2(ap[mi], bp[nj],
                                                         acc[mi][nj], false);
        }
        __syncthreads();
    }

    float4 bv = {0.f, 0.f, 0.f, 0.f};
    if (bias) bv = *(const float4*)&bias[n0 + 4 * tj];
    #pragma unroll
    for (int mi = 0; mi < 4; mi++) {
        const int m = m0 + 4 * ti + mi;
        h4 r = {(_Float16)(acc[mi][0] + bv.x), (_Float16)(acc[mi][1] + bv.y),
                (_Float16)(acc[mi][2] + bv.z), (_Float16)(acc[mi][3] + bv.w)};
        *(h4*)&Cc[m * 512 + n0 + 4 * tj] = r;
    }
}

// ---------------------------------------------------------------------------
// Core: partial[s][i][j] = sum_{h in 64-slab s} relu(hx[i,h]+hy[j,h])*w2[h]
// grid (8,8,8) = 512 blocks (2/CU), 256 threads, 4x4 register tile.
// f16 operands, v_dot2_f32_f16 accumulate. f16 partial output.
// (proven R4/R5 body -- LDS ~6.9K cy vs VALU ~6.1K cy per CU, balanced)
// ---------------------------------------------------------------------------
__global__ __launch_bounds__(256) void affinity_core(
    const _Float16* __restrict__ hx, const _Float16* __restrict__ hy,
    const float* __restrict__ w2, _Float16* __restrict__ partial)
{
    __shared__ __align__(16) _Float16 xs[64 * 72];
    __shared__ __align__(16) _Float16 ys[64 * 72];
    __shared__ __align__(16) _Float16 ws2[64];

    const int t  = threadIdx.x;
    const int i0 = blockIdx.x * 64;
    const int j0 = blockIdx.y * 64;
    const int h0 = blockIdx.z * 64;
    const int ti = t / 16;
    const int tj = t % 16;

    #pragma unroll
    for (int s = 0; s < 2; s++) {
        const int id = t + s * 256;
        const int r  = id >> 3;
        const int c8 = (id & 7) * 8;
        *(float4*)&xs[r * 72 + c8] = *(const float4*)&hx[(i0 + r) * 512 + h0 + c8];
        *(float4*)&ys[r * 72 + c8] = *(const float4*)&hy[(j0 + r) * 512 + h0 + c8];
    }
    if (t < 64) ws2[t] = (_Float16)w2[h0 + t];
    __syncthreads();

    float acc[4][4] = {};
    const _Float16* xr = xs + ti * 72;
    const _Float16* yr = ys + tj * 72;
    const h2 hz = {(_Float16)0.f, (_Float16)0.f};

    #pragma unroll 2
    for (int g = 0; g < 8; g++) {
        const int ho = g * 8;
        h8 w = *(const h8*)&ws2[ho];
        h8 x[4], y[4];
        #pragma unroll
        for (int m = 0; m < 4; m++) x[m] = *(const h8*)&xr[m * (16 * 72) + ho];
        #pragma unroll
        for (int n = 0; n < 4; n++) y[n] = *(const h8*)&yr[n * (16 * 72) + ho];
        const h2* wp = (const h2*)&w;
        #pragma unroll
        for (int m = 0; m < 4; m++) {
            const h2* xp = (const h2*)&x[m];
            #pragma unroll
            for (int n = 0; n < 4; n++) {
                const h2* yp = (const h2*)&y[n];
                float a = acc[m][n];
                #pragma unroll
                for (int p = 0; p < 4; p++) {
                    h2 s = xp[p] + yp[p];                           // v_pk_add_f16
                    s = __builtin_elementwise_max(s, hz);           // v_pk_max_f16
                    a = __builtin_amdgcn_fdot2(s, wp[p], a, false); // v_dot2_f32_f16
                }
                acc[m][n] = a;
            }
        }
    }

    _Float16* p = partial + blockIdx.z * (512 * 512);
    #pragma unroll
    for (int m = 0; m < 4; m++) {
        #pragma unroll
        for (int n = 0; n < 4; n++) {
            p[(i0 + ti + 16 * m) * 512 + (j0 + tj + 16 * n)] = (_Float16)acc[m][n];
        }
    }
}

// ---------------------------------------------------------------------------
// Final reduce: out = sum_{s<8} partial[s] + b2  (f16 partials, f32 out)
// ---------------------------------------------------------------------------
__global__ __launch_bounds__(256) void reduce8(
    const _Float16* __restrict__ partial, const float* __restrict__ b2,
    float* __restrict__ out)
{
    const int idx = (blockIdx.x * 256 + threadIdx.x) * 4;
    const float bb = b2[0];
    float4 r = {bb, bb, bb, bb};
    #pragma unroll
    for (int s = 0; s < 8; s++) {
        h4 p = *(const h4*)&partial[s * 262144 + idx];
        r.x += (float)p[0]; r.y += (float)p[1];
        r.z += (float)p[2]; r.w += (float)p[3];
    }
    *(float4*)&out[idx] = r;
}

extern "C" void kernel_launch(void* const* d_in, const int* in_sizes, int n_in,
                              void* d_out, int out_size, void* d_ws, size_t ws_size,
                              hipStream_t stream) {
    const float* X    = (const float*)d_in[0];  // 512x256
    const float* Y    = (const float*)d_in[1];  // 512x256
    const float* W_sr = (const float*)d_in[2];  // 256x256
    const float* W_tg = (const float*)d_in[3];  // 256x256
    const float* W1   = (const float*)d_in[4];  // 512x512 (H x 2C)
    const float* b1   = (const float*)d_in[5];  // 512
    const float* w2   = (const float*)d_in[6];  // 1x512
    const float* b2   = (const float*)d_in[7];  // 1

    float* ws = (float*)d_ws;
    _Float16* Xp      = (_Float16*)ws;               // 512x256 f16
    _Float16* Yp      = (_Float16*)(ws + 65536);     // 512x256 f16
    _Float16* hx      = (_Float16*)(ws + 131072);    // 512x512 f16
    _Float16* hy      = (_Float16*)(ws + 262144);    // 512x512 f16
    _Float16* partial = (_Float16*)(ws + 393216);    // 8 x 512x512 f16
    float* out = (float*)d_out;

    // Stage 1: Xp = X @ W_sr.T ; Yp = Y @ W_tg.T (dot2-f16)
    gemm1_f16<<<dim3(16, 8, 2), 128, 0, stream>>>(
        X, Y, W_sr, W_tg, Xp, Yp);
    // Stage 2: hx = Xp @ W1x.T ; hy = Yp @ W1y.T + b1 (dot2-f16)
    gemm2_f16<<<dim3(16, 8, 2), 128, 0, stream>>>(
        Xp, Yp, W1, W1 + 256, hx, hy, b1);
    // Stage 3: h-split relu reduction into 8 f16 partials (512 blocks = 2/CU)
    affinity_core<<<dim3(8, 8, 8), 256, 0, stream>>>(hx, hy, w2, partial);
    // Stage 4: sum partials + b2
    reduce8<<<256, 256, 0, stream>>>(partial, b2, out);
}